// Round 6
// baseline (568.375 us; speedup 1.0000x reference)
//
#include <hip/hip_runtime.h>
#include <cstdint>

// ---------------------------------------------------------------------------
// BayesianNetwork: 2x vMF-normalized GEMM(1024x4096x4096) + relu, gaussian
// last layer [4096->5] + log_softmax, plus closed-form scalar terms.
// Split-bf16 GEMM (hi*hi+hi*lo+lo*hi) on the 2.5PF MFMA pipe.
// R5: 2-phase double-buffered staging (T3-minimum); sumsq fused into the
// W-transpose pass; norm scale moved to GEMM epilogue.
// ---------------------------------------------------------------------------

#define NH (-0.9189385332046727)   // -0.5*log(2*pi)
#define DPI 3.141592653589793238462643383279502884

typedef short s16x8 __attribute__((ext_vector_type(8)));
typedef float f32x4 __attribute__((ext_vector_type(4)));

static __device__ __forceinline__ ushort f2bf(float f) {
  uint32_t u = __float_as_uint(f);
  u += 0x7fffu + ((u >> 16) & 1u);   // RNE
  return (ushort)(u >> 16);
}
static __device__ __forceinline__ float bf2f(ushort h) {
  return __uint_as_float(((uint32_t)h) << 16);
}

// global -> LDS direct copy, 16B per lane; LDS dest linear in lane id.
static __device__ __forceinline__ void gload16(const void* g, void* l) {
  __builtin_amdgcn_global_load_lds(
      (__attribute__((address_space(1))) void*)g,
      (__attribute__((address_space(3))) void*)l,
      16, 0, 0);
}

// --------------------------- reductions ------------------------------------
// mode 0: sum(x^2); mode 1: sum(log(log1p(exp(x)))). One partial per block.
__global__ void reduce_k(const float* __restrict__ x, int n,
                         double* __restrict__ part, int mode) {
  double a = 0.0;
  const int tid = blockIdx.x * blockDim.x + threadIdx.x;
  const int stride = gridDim.x * blockDim.x;
  const int n4 = n >> 2;
  for (int i = tid; i < n4; i += stride) {
    float4 v = reinterpret_cast<const float4*>(x)[i];
    if (mode == 0) {
      a += (double)v.x * v.x + (double)v.y * v.y +
           (double)v.z * v.z + (double)v.w * v.w;
    } else {
      a += log(log1p(exp((double)v.x)));
      a += log(log1p(exp((double)v.y)));
      a += log(log1p(exp((double)v.z)));
      a += log(log1p(exp((double)v.w)));
    }
  }
  for (int i = (n4 << 2) + tid; i < n; i += stride) {
    float v = x[i];
    a += (mode == 0) ? (double)v * v : log(log1p(exp((double)v)));
  }
  for (int o = 32; o > 0; o >>= 1) a += __shfl_down(a, o);
  __shared__ double red[4];
  if ((threadIdx.x & 63) == 0) red[threadIdx.x >> 6] = a;
  __syncthreads();
  if (threadIdx.x == 0) part[blockIdx.x] = red[0] + red[1] + red[2] + red[3];
}

// --------------------------- norm scalars ----------------------------------
// out2[0] = 1/sqrt(sum(pw)), out2[1] = 1/sqrt(sum(pb))
__global__ void norms_k(const double* __restrict__ pw, int nw,
                        const double* __restrict__ pb, int nb,
                        float* __restrict__ out2) {
  __shared__ double red[4];
  const int t = threadIdx.x;
  double s[2];
  const double* p[2] = {pw, pb};
  const int   cn[2] = {nw, nb};
  for (int q = 0; q < 2; q++) {
    double v = 0.0;
    for (int i = t; i < cn[q]; i += 256) v += p[q][i];
    for (int o = 32; o > 0; o >>= 1) v += __shfl_down(v, o);
    if ((t & 63) == 0) red[t >> 6] = v;
    __syncthreads();
    s[q] = red[0] + red[1] + red[2] + red[3];
    __syncthreads();
  }
  if (t == 0) {
    out2[0] = (float)(1.0 / sqrt(s[0]));
    out2[1] = (float)(1.0 / sqrt(s[1]));
  }
}

// --------------------------- scalar finalize -------------------------------
static __device__ double logC_vmf(double d, double kappa) {
  double s  = 0.5 * d - 1.0;
  double x  = kappa / s;
  double sq = sqrt(1.0 + x * x);
  double eta = sq + log(x) - log1p(sq);
  double lb  = s * eta - 0.5 * log(2.0 * DPI * s) - 0.5 * log(sq);
  return d * NH + s * log(kappa) - lb;
}

// P layout (doubles): Pw1[8192] @0, Pw2[8192] @8192, Pb1[8] @16384,
// Pb2[8] @16392, Pw3[8] @16400, Pb3[1] @16408, Pr3[8] @16409, Pbr3[1] @16417
__global__ void finalize_k(const double* __restrict__ P,
                           const float* lkw1, const float* lkb1,
                           const float* lkw2, const float* lkb2,
                           float* __restrict__ out_sc) {
  __shared__ double S[8];
  __shared__ double red[4];
  // S order: Sw1, Sb1, Sw2, Sb2, Sw3, Sb3, R6, R7
  const int offs[8] = {0, 16384, 8192, 16392, 16400, 16408, 16409, 16417};
  const int cnts[8] = {8192, 8, 8192, 8, 8, 1, 8, 1};
  const int t = threadIdx.x;
  for (int ai = 0; ai < 8; ai++) {
    double v = 0.0;
    for (int i = t; i < cnts[ai]; i += 256) v += P[offs[ai] + i];
    for (int o = 32; o > 0; o >>= 1) v += __shfl_down(v, o);
    if ((t & 63) == 0) red[t >> 6] = v;
    __syncthreads();
    if (t == 0) S[ai] = red[0] + red[1] + red[2] + red[3];
    __syncthreads();
  }
  if (t == 0) {
    double Sw3 = S[4], Sb3 = S[5], R6 = S[6], R7 = S[7];
    const double dw = 16777216.0, db = 4096.0;
    double kw1 = exp((double)lkw1[0]) + 1e-6;
    double kb1 = exp((double)lkb1[0]) + 1e-6;
    double kw2 = exp((double)lkw2[0]) + 1e-6;
    double kb2 = exp((double)lkb2[0]) + 1e-6;
    // dot(mu, mu) == 1 exactly (sumsq / norm^2)
    double lvp = kw1 + logC_vmf(dw, kw1) + kb1 + logC_vmf(db, kb1)
               + kw2 + logC_vmf(dw, kw2) + kb2 + logC_vmf(db, kb2)
               + 20485.0 * NH - R6 - R7;                 // gaussian layer lvp
    // reference: h stays f64 in h*log(pi); only gammaln's arg goes through f32
    double h64 = (dw + 1.0) * 0.5;                       // 8388608.5
    double hf  = (double)(float)h64;                     // 8388608.0
    double lsa = log(2.0) + h64 * log(DPI) - lgamma(hf);
    double lp  = -4.0 * lsa + 20485.0 * NH - 0.5 * (Sw3 + Sb3);
    out_sc[0] = (float)lvp;
    out_sc[1] = (float)lp;
  }
}

// --------------------------- bf16 hi/lo splitting --------------------------
__global__ void split_plain_k(const float* __restrict__ in,
                              ushort* __restrict__ hi, ushort* __restrict__ lo,
                              int n4) {
  int i = blockIdx.x * blockDim.x + threadIdx.x;
  if (i >= n4) return;
  float4 v = reinterpret_cast<const float4*>(in)[i];
  ushort4 h, l;
  h.x = f2bf(v.x); l.x = f2bf(v.x - bf2f(h.x));
  h.y = f2bf(v.y); l.y = f2bf(v.y - bf2f(h.y));
  h.z = f2bf(v.z); l.z = f2bf(v.z - bf2f(h.z));
  h.w = f2bf(v.w); l.w = f2bf(v.w - bf2f(h.w));
  reinterpret_cast<ushort4*>(hi)[i] = h;
  reinterpret_cast<ushort4*>(lo)[i] = l;
}

// W viewed [K=4096][N=4096] row-major -> WT hi/lo [N][K] (unscaled), plus
// per-block sum(x^2) partial (fused norm reduction; saves a full 67MB pass).
__global__ void split_transpose_k(const float* __restrict__ in,
                                  ushort* __restrict__ hi,
                                  ushort* __restrict__ lo,
                                  double* __restrict__ part) {
  __shared__ float tile[64][33];
  __shared__ double red[4];
  const int tx = threadIdx.x, ty = threadIdx.y;  // (32,8)
  const int n0 = blockIdx.x * 32, k0 = blockIdx.y * 64;
  double a = 0.0;
#pragma unroll
  for (int r = 0; r < 8; r++) {
    float v = in[(size_t)(k0 + ty + r * 8) * 4096 + n0 + tx];
    tile[ty + r * 8][tx] = v;
    a += (double)v * v;
  }
  __syncthreads();
#pragma unroll
  for (int r = 0; r < 4; r++) {
    const int nn = ty + r * 8;
    float v0 = tile[2 * tx][nn];
    float v1 = tile[2 * tx + 1][nn];
    ushort2 h, l;
    h.x = f2bf(v0); l.x = f2bf(v0 - bf2f(h.x));
    h.y = f2bf(v1); l.y = f2bf(v1 - bf2f(h.y));
    size_t o = ((size_t)(n0 + nn) * 4096 + k0 + 2 * tx) >> 1;  // ushort2 index
    reinterpret_cast<ushort2*>(hi)[o] = h;
    reinterpret_cast<ushort2*>(lo)[o] = l;
  }
  // block-reduce the sumsq partial
  const int tid = ty * 32 + tx;
  for (int o = 32; o > 0; o >>= 1) a += __shfl_down(a, o);
  if ((tid & 63) == 0) red[tid >> 6] = a;
  __syncthreads();
  if (tid == 0)
    part[blockIdx.y * gridDim.x + blockIdx.x] = red[0] + red[1] + red[2] + red[3];
}

// --------------------------- split-bf16 GEMM -------------------------------
// C[64x128]/block, BK=32, 4 waves (2x2, wave tile 32x64), 3 MFMAs per pair.
// 2-phase double-buffered staging: issue next tile's global_load_lds BEFORE
// computing the current tile; single barrier per K-step (vmcnt(0) drain then
// has a full compute phase of slack). A:[M][K], B:[N][K] hi/lo bf16.
// epilogue: v = relu(acc*wsc + bias[col]*bsc); mode0 -> hi/lo bf16, 1 -> f32.
__global__ __launch_bounds__(256) void gemm_split_k(
    const ushort* __restrict__ Ahi, const ushort* __restrict__ Alo,
    const ushort* __restrict__ Bhi, const ushort* __restrict__ Blo,
    const float* __restrict__ bias, const float* __restrict__ scales,
    ushort* __restrict__ Ohi, ushort* __restrict__ Olo,
    float* __restrict__ Of,
    int M, int N, int K, int mode) {
  __shared__ ushort As[2][2][64 * 32];    // [buf][hi/lo]
  __shared__ ushort Bs[2][2][128 * 32];   // 48 KB total
  const int t = threadIdx.x;
  const int lane = t & 63, wid = t >> 6;
  const int wm = wid >> 1, wn = wid & 1;
  const int bm = blockIdx.y, bn = blockIdx.x;
  const int lr = lane & 15, lk = (lane >> 4) * 8;

  f32x4 acc[2][4];
#pragma unroll
  for (int i = 0; i < 2; i++)
#pragma unroll
    for (int j = 0; j < 4; j++) acc[i][j] = (f32x4){0.f, 0.f, 0.f, 0.f};

  const size_t arow = (size_t)(bm * 64) * K;
  const size_t brow = (size_t)(bn * 128) * K;
  const int ar = t >> 2, ac = (t & 3) * 8;      // A: 64 rows x 4 chunks

  auto STAGE = [&](int buf, int k0) {
    const size_t ga = arow + (size_t)ar * K + k0 + ac;
    gload16(Ahi + ga, &As[buf][0][t * 8]);
    gload16(Alo + ga, &As[buf][1][t * 8]);
#pragma unroll
    for (int q = 0; q < 2; q++) {
      const int L = q * 256 + t;
      const size_t gb = brow + (size_t)(L >> 2) * K + k0 + (L & 3) * 8;
      gload16(Bhi + gb, &Bs[buf][0][L * 8]);
      gload16(Blo + gb, &Bs[buf][1][L * 8]);
    }
  };

  auto COMPUTE = [&](int buf) {
    s16x8 ah[2], al[2], bh[4], bl[4];
#pragma unroll
    for (int i = 0; i < 2; i++) {
      const int ra = (wm * 32 + i * 16 + lr) * 32 + lk;
      ah[i] = *(const s16x8*)&As[buf][0][ra];
      al[i] = *(const s16x8*)&As[buf][1][ra];
    }
#pragma unroll
    for (int j = 0; j < 4; j++) {
      const int rb = (wn * 64 + j * 16 + lr) * 32 + lk;
      bh[j] = *(const s16x8*)&Bs[buf][0][rb];
      bl[j] = *(const s16x8*)&Bs[buf][1][rb];
    }
#pragma unroll
    for (int i = 0; i < 2; i++)
#pragma unroll
      for (int j = 0; j < 4; j++) {
        acc[i][j] = __builtin_amdgcn_mfma_f32_16x16x32_bf16(ah[i], bh[j], acc[i][j], 0, 0, 0);
        acc[i][j] = __builtin_amdgcn_mfma_f32_16x16x32_bf16(ah[i], bl[j], acc[i][j], 0, 0, 0);
        acc[i][j] = __builtin_amdgcn_mfma_f32_16x16x32_bf16(al[i], bh[j], acc[i][j], 0, 0, 0);
      }
  };

  // 2-phase pipeline
  STAGE(0, 0);
  __syncthreads();
  int cur = 0;
  for (int k0 = 32; k0 < K; k0 += 32) {
    STAGE(cur ^ 1, k0);   // issue next tile (latency hides under COMPUTE)
    COMPUTE(cur);
    __syncthreads();      // vmcnt(0)+lgkmcnt(0) drain + barrier
    cur ^= 1;
  }
  COMPUTE(cur);

  const float wsc = scales[0], bsc = scales[1];
  const int rb0 = bm * 64 + wm * 32 + (lane >> 4) * 4;
  const int cb0 = bn * 128 + wn * 64 + lr;
#pragma unroll
  for (int j = 0; j < 4; j++) {
    const int col = cb0 + j * 16;
    const float bv = bias[col] * bsc;
#pragma unroll
    for (int i = 0; i < 2; i++) {
#pragma unroll
      for (int r = 0; r < 4; r++) {
        const int row = rb0 + i * 16 + r;
        float v = fmaxf(fmaf(acc[i][j][r], wsc, bv), 0.0f);
        const size_t o = (size_t)row * N + col;
        if (mode == 0) {
          ushort h = f2bf(v);
          Ohi[o] = h;
          Olo[o] = f2bf(v - bf2f(h));
        } else {
          Of[o] = v;
        }
      }
    }
  }
}

// --------------------------- last layer + log_softmax ----------------------
__global__ void layer3_k(const float* __restrict__ h2,
                         const float* __restrict__ w3,
                         const float* __restrict__ b3,
                         float* __restrict__ out) {
  const int row = blockIdx.x;
  const int t = threadIdx.x;
  const float* hr = h2 + (size_t)row * 4096;
  float a[5] = {0.f, 0.f, 0.f, 0.f, 0.f};
  for (int k = t; k < 4096; k += 256) {
    const float h = hr[k];
#pragma unroll
    for (int o = 0; o < 5; o++) a[o] += h * w3[o * 4096 + k];
  }
#pragma unroll
  for (int o = 0; o < 5; o++)
    for (int s = 32; s > 0; s >>= 1) a[o] += __shfl_down(a[o], s);
  __shared__ float red[4][5];
  if ((t & 63) == 0) {
#pragma unroll
    for (int o = 0; o < 5; o++) red[t >> 6][o] = a[o];
  }
  __syncthreads();
  if (t == 0) {
    float y[5];
#pragma unroll
    for (int o = 0; o < 5; o++)
      y[o] = red[0][o] + red[1][o] + red[2][o] + red[3][o] + b3[o];
    float m = y[0];
    for (int o = 1; o < 5; o++) m = fmaxf(m, y[o]);
    float ssum = 0.f;
    for (int o = 0; o < 5; o++) ssum += expf(y[o] - m);
    const float ls = m + logf(ssum);
    for (int o = 0; o < 5; o++) out[row * 5 + o] = y[o] - ls;
  }
}

// --------------------------- launcher --------------------------------------
extern "C" void kernel_launch(void* const* d_in, const int* in_sizes, int n_in,
                              void* d_out, int out_size, void* d_ws, size_t ws_size,
                              hipStream_t stream) {
  const float* x     = (const float*)d_in[0];
  const float* w1mu  = (const float*)d_in[1];
  const float* lkw1  = (const float*)d_in[2];
  const float* b1mu  = (const float*)d_in[3];
  const float* lkb1  = (const float*)d_in[4];
  const float* w2mu  = (const float*)d_in[5];
  const float* lkw2  = (const float*)d_in[6];
  const float* b2mu  = (const float*)d_in[7];
  const float* lkb2  = (const float*)d_in[8];
  const float* w3mu  = (const float*)d_in[9];
  const float* w3rho = (const float*)d_in[10];
  const float* b3mu  = (const float*)d_in[11];
  const float* b3rho = (const float*)d_in[12];
  float* outp = (float*)d_out;

  // workspace layout (~96.3 MB)
  char* w = (char*)d_ws;
  double* P    = (double*)w;          // partials, 16418 doubles (~131 KB)
  double* Pw1  = P;                   // 8192
  double* Pw2  = P + 8192;            // 8192
  double* Pb1  = P + 16384;           // 8
  double* Pb2  = P + 16392;           // 8
  double* Pw3  = P + 16400;           // 8
  double* Pb3  = P + 16408;           // 1
  double* Pr3  = P + 16409;           // 8
  double* Pbr3 = P + 16417;           // 1
  float* params = (float*)(w + 140 * 1024);               // [0..3]
  ushort* xhi  = (ushort*)(w + 256 * 1024);               // 1024x4096 bf16
  ushort* xlo  = xhi  + (size_t)1024 * 4096;
  ushort* h1hi = xlo  + (size_t)1024 * 4096;
  ushort* h1lo = h1hi + (size_t)1024 * 4096;
  ushort* wthi = (ushort*)(h1lo + (size_t)1024 * 4096);   // 4096x4096 bf16
  ushort* wtlo = wthi + (size_t)4096 * 4096;
  float*  h2   = (float*)xhi;   // reuse x hi/lo region (dead after GEMM1)

  // preprocessing + reductions
  split_plain_k<<<4096, 256, 0, stream>>>(x, xhi, xlo, 1048576);
  split_transpose_k<<<dim3(128, 64), dim3(32, 8), 0, stream>>>(w1mu, wthi, wtlo, Pw1);
  reduce_k<<<8, 256, 0, stream>>>(b1mu, 4096, Pb1, 0);
  reduce_k<<<8, 256, 0, stream>>>(w3mu, 20480, Pw3, 0);
  reduce_k<<<1, 256, 0, stream>>>(b3mu, 5, Pb3, 0);
  reduce_k<<<8, 256, 0, stream>>>(w3rho, 20480, Pr3, 1);
  reduce_k<<<1, 256, 0, stream>>>(b3rho, 5, Pbr3, 1);
  norms_k<<<1, 256, 0, stream>>>(Pw1, 8192, Pb1, 8, params + 0);
  // layer 1: h1 = relu((x @ W1)*wsc + b1*bsc) -> bf16 hi/lo
  gemm_split_k<<<dim3(32, 16), 256, 0, stream>>>(xhi, xlo, wthi, wtlo,
                                                 b1mu, params + 0,
                                                 h1hi, h1lo, nullptr,
                                                 1024, 4096, 4096, 0);
  // layer 2 prep + GEMM -> f32 h2
  split_transpose_k<<<dim3(128, 64), dim3(32, 8), 0, stream>>>(w2mu, wthi, wtlo, Pw2);
  reduce_k<<<8, 256, 0, stream>>>(b2mu, 4096, Pb2, 0);
  norms_k<<<1, 256, 0, stream>>>(Pw2, 8192, Pb2, 8, params + 2);
  gemm_split_k<<<dim3(32, 16), 256, 0, stream>>>(h1hi, h1lo, wthi, wtlo,
                                                 b2mu, params + 2,
                                                 nullptr, nullptr, h2,
                                                 1024, 4096, 4096, 1);
  // scalars + last layer
  finalize_k<<<1, 256, 0, stream>>>(P, lkw1, lkb1, lkw2, lkb2, outp + 5120);
  layer3_k<<<1024, 256, 0, stream>>>(h2, w3mu, b3mu, outp);
}

// Round 8
// 527.238 us; speedup vs baseline: 1.0780x; 1.0780x over previous
//
#include <hip/hip_runtime.h>
#include <cstdint>

// ---------------------------------------------------------------------------
// BayesianNetwork: 2x vMF-normalized GEMM(1024x4096x4096) + relu, gaussian
// last layer [4096->5] + log_softmax, plus closed-form scalar terms.
// Split-bf16 GEMM (hi*hi+hi*lo+lo*hi) on the 2.5PF MFMA pipe.
// R7: revert GEMM loop to R4 structure (R5 dbuf regressed: compiler alias-
// serializes ds_read vs global_load_lds). Split-K=2 -> 1024 blocks = 4/CU
// (m114 cross-block overlap hides barrier drain). Merged small reductions.
// ---------------------------------------------------------------------------

#define NH (-0.9189385332046727)   // -0.5*log(2*pi)
#define DPI 3.141592653589793238462643383279502884

typedef short s16x8 __attribute__((ext_vector_type(8)));
typedef float f32x4 __attribute__((ext_vector_type(4)));

static __device__ __forceinline__ ushort f2bf(float f) {
  uint32_t u = __float_as_uint(f);
  u += 0x7fffu + ((u >> 16) & 1u);   // RNE
  return (ushort)(u >> 16);
}
static __device__ __forceinline__ float bf2f(ushort h) {
  return __uint_as_float(((uint32_t)h) << 16);
}

// global -> LDS direct copy, 16B per lane; LDS dest linear in lane id.
static __device__ __forceinline__ void gload16(const void* g, void* l) {
  __builtin_amdgcn_global_load_lds(
      (__attribute__((address_space(1))) void*)g,
      (__attribute__((address_space(3))) void*)l,
      16, 0, 0);
}

// --------------------------- small reductions (one launch) -----------------
// P layout (doubles): Pw1[8192]@0, Pw2[8192]@8192, Pb1[8]@16384, Pb2[8]@16392,
// Pw3[8]@16400, Pb3[1]@16408, Pr3[8]@16409, Pbr3[1]@16417
__global__ void small_reduce_k(const float* __restrict__ b1,
                               const float* __restrict__ b2,
                               const float* __restrict__ w3,
                               const float* __restrict__ b3,
                               const float* __restrict__ r3,
                               const float* __restrict__ br3,
                               double* __restrict__ P) {
  const int bid = blockIdx.x;
  const float* x; int n, lb, nb, mode; double* out;
  if (bid < 8)        { x = b1;  n = 4096;  lb = bid;      nb = 8; mode = 0; out = P + 16384; }
  else if (bid < 16)  { x = b2;  n = 4096;  lb = bid - 8;  nb = 8; mode = 0; out = P + 16392; }
  else if (bid < 24)  { x = w3;  n = 20480; lb = bid - 16; nb = 8; mode = 0; out = P + 16400; }
  else if (bid == 24) { x = b3;  n = 5;     lb = 0;        nb = 1; mode = 0; out = P + 16408; }
  else if (bid < 33)  { x = r3;  n = 20480; lb = bid - 25; nb = 8; mode = 1; out = P + 16409; }
  else                { x = br3; n = 5;     lb = 0;        nb = 1; mode = 1; out = P + 16417; }
  double a = 0.0;
  const int tid = lb * 256 + threadIdx.x, stride = nb * 256;
  for (int i = tid; i < n; i += stride) {
    float v = x[i];
    a += (mode == 0) ? (double)v * v : log(log1p(exp((double)v)));
  }
  for (int o = 32; o > 0; o >>= 1) a += __shfl_down(a, o);
  __shared__ double red[4];
  if ((threadIdx.x & 63) == 0) red[threadIdx.x >> 6] = a;
  __syncthreads();
  if (threadIdx.x == 0) out[lb] = red[0] + red[1] + red[2] + red[3];
}

// --------------------------- norm scalars ----------------------------------
__global__ void norms_k(const double* __restrict__ pw, int nw,
                        const double* __restrict__ pb, int nb,
                        float* __restrict__ out2) {
  __shared__ double red[4];
  const int t = threadIdx.x;
  double s[2];
  const double* p[2] = {pw, pb};
  const int   cn[2] = {nw, nb};
  for (int q = 0; q < 2; q++) {
    double v = 0.0;
    for (int i = t; i < cn[q]; i += 256) v += p[q][i];
    for (int o = 32; o > 0; o >>= 1) v += __shfl_down(v, o);
    if ((t & 63) == 0) red[t >> 6] = v;
    __syncthreads();
    s[q] = red[0] + red[1] + red[2] + red[3];
    __syncthreads();
  }
  if (t == 0) {
    out2[0] = (float)(1.0 / sqrt(s[0]));
    out2[1] = (float)(1.0 / sqrt(s[1]));
  }
}

// --------------------------- scalar finalize -------------------------------
static __device__ double logC_vmf(double d, double kappa) {
  double s  = 0.5 * d - 1.0;
  double x  = kappa / s;
  double sq = sqrt(1.0 + x * x);
  double eta = sq + log(x) - log1p(sq);
  double lb  = s * eta - 0.5 * log(2.0 * DPI * s) - 0.5 * log(sq);
  return d * NH + s * log(kappa) - lb;
}

__global__ void finalize_k(const double* __restrict__ P,
                           const float* lkw1, const float* lkb1,
                           const float* lkw2, const float* lkb2,
                           float* __restrict__ out_sc) {
  __shared__ double S[8];
  __shared__ double red[4];
  // S order: Sw1, Sb1, Sw2, Sb2, Sw3, Sb3, R6, R7
  const int offs[8] = {0, 16384, 8192, 16392, 16400, 16408, 16409, 16417};
  const int cnts[8] = {8192, 8, 8192, 8, 8, 1, 8, 1};
  const int t = threadIdx.x;
  for (int ai = 0; ai < 8; ai++) {
    double v = 0.0;
    for (int i = t; i < cnts[ai]; i += 256) v += P[offs[ai] + i];
    for (int o = 32; o > 0; o >>= 1) v += __shfl_down(v, o);
    if ((t & 63) == 0) red[t >> 6] = v;
    __syncthreads();
    if (t == 0) S[ai] = red[0] + red[1] + red[2] + red[3];
    __syncthreads();
  }
  if (t == 0) {
    double Sw3 = S[4], Sb3 = S[5], R6 = S[6], R7 = S[7];
    const double dw = 16777216.0, db = 4096.0;
    double kw1 = exp((double)lkw1[0]) + 1e-6;
    double kb1 = exp((double)lkb1[0]) + 1e-6;
    double kw2 = exp((double)lkw2[0]) + 1e-6;
    double kb2 = exp((double)lkb2[0]) + 1e-6;
    // dot(mu, mu) == 1 exactly (sumsq / norm^2)
    double lvp = kw1 + logC_vmf(dw, kw1) + kb1 + logC_vmf(db, kb1)
               + kw2 + logC_vmf(dw, kw2) + kb2 + logC_vmf(db, kb2)
               + 20485.0 * NH - R6 - R7;                 // gaussian layer lvp
    // reference: h stays f64 in h*log(pi); only gammaln's arg goes through f32
    double h64 = (dw + 1.0) * 0.5;                       // 8388608.5
    double hf  = (double)(float)h64;                     // 8388608.0
    double lsa = log(2.0) + h64 * log(DPI) - lgamma(hf);
    double lp  = -4.0 * lsa + 20485.0 * NH - 0.5 * (Sw3 + Sb3);
    out_sc[0] = (float)lvp;
    out_sc[1] = (float)lp;
  }
}

// --------------------------- bf16 hi/lo splitting --------------------------
__global__ void split_plain_k(const float* __restrict__ in,
                              ushort* __restrict__ hi, ushort* __restrict__ lo,
                              int n4) {
  int i = blockIdx.x * blockDim.x + threadIdx.x;
  if (i >= n4) return;
  float4 v = reinterpret_cast<const float4*>(in)[i];
  ushort4 h, l;
  h.x = f2bf(v.x); l.x = f2bf(v.x - bf2f(h.x));
  h.y = f2bf(v.y); l.y = f2bf(v.y - bf2f(h.y));
  h.z = f2bf(v.z); l.z = f2bf(v.z - bf2f(h.z));
  h.w = f2bf(v.w); l.w = f2bf(v.w - bf2f(h.w));
  reinterpret_cast<ushort4*>(hi)[i] = h;
  reinterpret_cast<ushort4*>(lo)[i] = l;
}

// W viewed [K=4096][N=4096] row-major -> WT hi/lo [N][K] (unscaled), plus
// per-block sum(x^2) partial (fused norm reduction).
__global__ void split_transpose_k(const float* __restrict__ in,
                                  ushort* __restrict__ hi,
                                  ushort* __restrict__ lo,
                                  double* __restrict__ part) {
  __shared__ float tile[64][33];
  __shared__ double red[4];
  const int tx = threadIdx.x, ty = threadIdx.y;  // (32,8)
  const int n0 = blockIdx.x * 32, k0 = blockIdx.y * 64;
  double a = 0.0;
#pragma unroll
  for (int r = 0; r < 8; r++) {
    float v = in[(size_t)(k0 + ty + r * 8) * 4096 + n0 + tx];
    tile[ty + r * 8][tx] = v;
    a += (double)v * v;
  }
  __syncthreads();
#pragma unroll
  for (int r = 0; r < 4; r++) {
    const int nn = ty + r * 8;
    float v0 = tile[2 * tx][nn];
    float v1 = tile[2 * tx + 1][nn];
    ushort2 h, l;
    h.x = f2bf(v0); l.x = f2bf(v0 - bf2f(h.x));
    h.y = f2bf(v1); l.y = f2bf(v1 - bf2f(h.y));
    size_t o = ((size_t)(n0 + nn) * 4096 + k0 + 2 * tx) >> 1;  // ushort2 index
    reinterpret_cast<ushort2*>(hi)[o] = h;
    reinterpret_cast<ushort2*>(lo)[o] = l;
  }
  const int tid = ty * 32 + tx;
  for (int o = 32; o > 0; o >>= 1) a += __shfl_down(a, o);
  if ((tid & 63) == 0) red[tid >> 6] = a;
  __syncthreads();
  if (tid == 0)
    part[blockIdx.y * gridDim.x + blockIdx.x] = red[0] + red[1] + red[2] + red[3];
}

// --------------------------- split-bf16 GEMM -------------------------------
// C[64x128]/block, BK=32, 4 waves (2x2, wave tile 32x64), 3 MFMAs per pair.
// R4-proven loop: STAGE -> barrier -> COMPUTE -> barrier (single LDS buffer;
// cross-block overlap at 4 blocks/CU hides the vmcnt drain).
// Each block covers K range [z*ksize, (z+1)*ksize).
// mode 0: relu(acc*wsc+bias*bsc) -> hi/lo bf16. mode 1: same -> f32.
// mode 2: raw f32 partial to Of + z*M*N (split-K; combine applies epilogue).
__global__ __launch_bounds__(256) void gemm_split_k(
    const ushort* __restrict__ Ahi, const ushort* __restrict__ Alo,
    const ushort* __restrict__ Bhi, const ushort* __restrict__ Blo,
    const float* __restrict__ bias, const float* __restrict__ scales,
    ushort* __restrict__ Ohi, ushort* __restrict__ Olo,
    float* __restrict__ Of,
    int M, int N, int K, int ksize, int mode) {
  __shared__ ushort As[2][64 * 32];
  __shared__ ushort Bs[2][128 * 32];
  const int t = threadIdx.x;
  const int lane = t & 63, wid = t >> 6;
  const int wm = wid >> 1, wn = wid & 1;
  const int bm = blockIdx.y, bn = blockIdx.x;
  const int lr = lane & 15, lk = (lane >> 4) * 8;

  f32x4 acc[2][4];
#pragma unroll
  for (int i = 0; i < 2; i++)
#pragma unroll
    for (int j = 0; j < 4; j++) acc[i][j] = (f32x4){0.f, 0.f, 0.f, 0.f};

  const size_t arow = (size_t)(bm * 64) * K;
  const size_t brow = (size_t)(bn * 128) * K;
  const int ar = t >> 2, ac = (t & 3) * 8;      // A: 64 rows x 4 chunks
  const int kbeg = blockIdx.z * ksize;
  const int kend = kbeg + ksize;

  for (int k0 = kbeg; k0 < kend; k0 += 32) {
    {
      const size_t ga = arow + (size_t)ar * K + k0 + ac;
      gload16(Ahi + ga, &As[0][t * 8]);
      gload16(Alo + ga, &As[1][t * 8]);
    }
#pragma unroll
    for (int q = 0; q < 2; q++) {
      const int L = q * 256 + t;
      const size_t gb = brow + (size_t)(L >> 2) * K + k0 + (L & 3) * 8;
      gload16(Bhi + gb, &Bs[0][L * 8]);
      gload16(Blo + gb, &Bs[1][L * 8]);
    }
    __syncthreads();
    s16x8 ah[2], al[2], bh[4], bl[4];
#pragma unroll
    for (int i = 0; i < 2; i++) {
      const int ra = (wm * 32 + i * 16 + lr) * 32 + lk;
      ah[i] = *(const s16x8*)&As[0][ra];
      al[i] = *(const s16x8*)&As[1][ra];
    }
#pragma unroll
    for (int j = 0; j < 4; j++) {
      const int rb = (wn * 64 + j * 16 + lr) * 32 + lk;
      bh[j] = *(const s16x8*)&Bs[0][rb];
      bl[j] = *(const s16x8*)&Bs[1][rb];
    }
#pragma unroll
    for (int i = 0; i < 2; i++)
#pragma unroll
      for (int j = 0; j < 4; j++) {
        acc[i][j] = __builtin_amdgcn_mfma_f32_16x16x32_bf16(ah[i], bh[j], acc[i][j], 0, 0, 0);
        acc[i][j] = __builtin_amdgcn_mfma_f32_16x16x32_bf16(ah[i], bl[j], acc[i][j], 0, 0, 0);
        acc[i][j] = __builtin_amdgcn_mfma_f32_16x16x32_bf16(al[i], bh[j], acc[i][j], 0, 0, 0);
      }
    __syncthreads();
  }

  const int rb0 = bm * 64 + wm * 32 + (lane >> 4) * 4;
  const int cb0 = bn * 128 + wn * 64 + lr;
  if (mode == 2) {
    float* Op = Of + (size_t)blockIdx.z * ((size_t)M * N);
#pragma unroll
    for (int j = 0; j < 4; j++) {
      const int col = cb0 + j * 16;
#pragma unroll
      for (int i = 0; i < 2; i++)
#pragma unroll
        for (int r = 0; r < 4; r++)
          Op[(size_t)(rb0 + i * 16 + r) * N + col] = acc[i][j][r];
    }
    return;
  }
  const float wsc = scales[0], bsc = scales[1];
#pragma unroll
  for (int j = 0; j < 4; j++) {
    const int col = cb0 + j * 16;
    const float bv = bias[col] * bsc;
#pragma unroll
    for (int i = 0; i < 2; i++) {
#pragma unroll
      for (int r = 0; r < 4; r++) {
        const int row = rb0 + i * 16 + r;
        float v = fmaxf(fmaf(acc[i][j][r], wsc, bv), 0.0f);
        const size_t o = (size_t)row * N + col;
        if (mode == 0) {
          ushort h = f2bf(v);
          Ohi[o] = h;
          Olo[o] = f2bf(v - bf2f(h));
        } else {
          Of[o] = v;
        }
      }
    }
  }
}

// --------------------------- split-K combine + epilogue --------------------
// v = relu((p0+p1)*wsc + bias*bsc); mode 0 -> hi/lo bf16, mode 1 -> f32.
__global__ void combine_k(const float* __restrict__ p,
                          const float* __restrict__ bias,
                          const float* __restrict__ sc,
                          ushort* __restrict__ Ohi, ushort* __restrict__ Olo,
                          float* __restrict__ Of, int mode) {
  const int i = blockIdx.x * blockDim.x + threadIdx.x;   // float4 index, 1M
  const float wsc = sc[0], bsc = sc[1];
  float4 a = reinterpret_cast<const float4*>(p)[i];
  float4 b = reinterpret_cast<const float4*>(p + 4194304)[i];
  float4 bv = *reinterpret_cast<const float4*>(bias + ((i * 4) & 4095));
  float4 v;
  v.x = fmaxf(fmaf(a.x + b.x, wsc, bv.x * bsc), 0.f);
  v.y = fmaxf(fmaf(a.y + b.y, wsc, bv.y * bsc), 0.f);
  v.z = fmaxf(fmaf(a.z + b.z, wsc, bv.z * bsc), 0.f);
  v.w = fmaxf(fmaf(a.w + b.w, wsc, bv.w * bsc), 0.f);
  if (mode == 0) {
    ushort4 h, l;
    h.x = f2bf(v.x); l.x = f2bf(v.x - bf2f(h.x));
    h.y = f2bf(v.y); l.y = f2bf(v.y - bf2f(h.y));
    h.z = f2bf(v.z); l.z = f2bf(v.z - bf2f(h.z));
    h.w = f2bf(v.w); l.w = f2bf(v.w - bf2f(h.w));
    reinterpret_cast<ushort4*>(Ohi)[i] = h;
    reinterpret_cast<ushort4*>(Olo)[i] = l;
  } else {
    reinterpret_cast<float4*>(Of)[i] = v;
  }
}

// --------------------------- last layer + log_softmax ----------------------
__global__ void layer3_k(const float* __restrict__ h2,
                         const float* __restrict__ w3,
                         const float* __restrict__ b3,
                         float* __restrict__ out) {
  const int row = blockIdx.x;
  const int t = threadIdx.x;
  const float* hr = h2 + (size_t)row * 4096;
  float a[5] = {0.f, 0.f, 0.f, 0.f, 0.f};
  for (int k = t; k < 4096; k += 256) {
    const float h = hr[k];
#pragma unroll
    for (int o = 0; o < 5; o++) a[o] += h * w3[o * 4096 + k];
  }
#pragma unroll
  for (int o = 0; o < 5; o++)
    for (int s = 32; s > 0; s >>= 1) a[o] += __shfl_down(a[o], s);
  __shared__ float red[4][5];
  if ((t & 63) == 0) {
#pragma unroll
    for (int o = 0; o < 5; o++) red[t >> 6][o] = a[o];
  }
  __syncthreads();
  if (t == 0) {
    float y[5];
#pragma unroll
    for (int o = 0; o < 5; o++)
      y[o] = red[0][o] + red[1][o] + red[2][o] + red[3][o] + b3[o];
    float m = y[0];
    for (int o = 1; o < 5; o++) m = fmaxf(m, y[o]);
    float ssum = 0.f;
    for (int o = 0; o < 5; o++) ssum += expf(y[o] - m);
    const float ls = m + logf(ssum);
    for (int o = 0; o < 5; o++) out[row * 5 + o] = y[o] - ls;
  }
}

// --------------------------- launcher --------------------------------------
extern "C" void kernel_launch(void* const* d_in, const int* in_sizes, int n_in,
                              void* d_out, int out_size, void* d_ws, size_t ws_size,
                              hipStream_t stream) {
  const float* x     = (const float*)d_in[0];
  const float* w1mu  = (const float*)d_in[1];
  const float* lkw1  = (const float*)d_in[2];
  const float* b1mu  = (const float*)d_in[3];
  const float* lkb1  = (const float*)d_in[4];
  const float* w2mu  = (const float*)d_in[5];
  const float* lkw2  = (const float*)d_in[6];
  const float* b2mu  = (const float*)d_in[7];
  const float* lkb2  = (const float*)d_in[8];
  const float* w3mu  = (const float*)d_in[9];
  const float* w3rho = (const float*)d_in[10];
  const float* b3mu  = (const float*)d_in[11];
  const float* b3rho = (const float*)d_in[12];
  float* outp = (float*)d_out;

  // workspace layout: 256KB header + 32MB x/h1 + 64MB wt (+32MB partials)
  char* w = (char*)d_ws;
  double* P    = (double*)w;          // partials, 16418 doubles (~131 KB)
  double* Pw1  = P;                   // 8192
  double* Pw2  = P + 8192;            // 8192
  float* params = (float*)(w + 140 * 1024);               // [0..3]
  ushort* xhi  = (ushort*)(w + 256 * 1024);               // 1024x4096 bf16
  ushort* xlo  = xhi  + (size_t)1024 * 4096;
  ushort* h1hi = xlo  + (size_t)1024 * 4096;
  ushort* h1lo = h1hi + (size_t)1024 * 4096;
  ushort* wthi = (ushort*)(h1lo + (size_t)1024 * 4096);   // 4096x4096 bf16
  ushort* wtlo = wthi + (size_t)4096 * 4096;
  float*  part = (float*)(wtlo + (size_t)4096 * 4096);    // 2 x 16MB f32
  float*  h2   = (float*)xhi;   // reuse x hi/lo region (dead after GEMM1)

  // split-K=2 needs 128.3MB of ws; fall back deterministically otherwise.
  const bool splitk = ws_size >= (size_t)134479872;

  split_plain_k<<<4096, 256, 0, stream>>>(x, xhi, xlo, 1048576);
  split_transpose_k<<<dim3(128, 64), dim3(32, 8), 0, stream>>>(w1mu, wthi, wtlo, Pw1);
  small_reduce_k<<<34, 256, 0, stream>>>(b1mu, b2mu, w3mu, b3mu, w3rho, b3rho, P);
  norms_k<<<1, 256, 0, stream>>>(Pw1, 8192, P + 16384, 8, params + 0);
  // layer 1: h1 = relu((x @ W1n) + b1n) -> bf16 hi/lo
  if (splitk) {
    gemm_split_k<<<dim3(32, 16, 2), 256, 0, stream>>>(
        xhi, xlo, wthi, wtlo, nullptr, nullptr, nullptr, nullptr, part,
        1024, 4096, 4096, 2048, 2);
    combine_k<<<4096, 256, 0, stream>>>(part, b1mu, params + 0,
                                        h1hi, h1lo, nullptr, 0);
  } else {
    gemm_split_k<<<dim3(32, 16, 1), 256, 0, stream>>>(
        xhi, xlo, wthi, wtlo, b1mu, params + 0, h1hi, h1lo, nullptr,
        1024, 4096, 4096, 4096, 0);
  }
  // layer 2 prep + GEMM -> f32 h2
  split_transpose_k<<<dim3(128, 64), dim3(32, 8), 0, stream>>>(w2mu, wthi, wtlo, Pw2);
  norms_k<<<1, 256, 0, stream>>>(Pw2, 8192, P + 16392, 8, params + 2);
  if (splitk) {
    gemm_split_k<<<dim3(32, 16, 2), 256, 0, stream>>>(
        h1hi, h1lo, wthi, wtlo, nullptr, nullptr, nullptr, nullptr, part,
        1024, 4096, 4096, 2048, 2);
    combine_k<<<4096, 256, 0, stream>>>(part, b2mu, params + 2,
                                        nullptr, nullptr, h2, 1);
  } else {
    gemm_split_k<<<dim3(32, 16, 1), 256, 0, stream>>>(
        h1hi, h1lo, wthi, wtlo, b2mu, params + 2, nullptr, nullptr, h2,
        1024, 4096, 4096, 4096, 1);
  }
  // scalars + last layer
  finalize_k<<<1, 256, 0, stream>>>(P, lkw1, lkb1, lkw2, lkb2, outp + 5120);
  layer3_k<<<1024, 256, 0, stream>>>(h2, w3mu, b3mu, outp);
}

// Round 10
// 475.548 us; speedup vs baseline: 1.1952x; 1.1087x over previous
//
#include <hip/hip_runtime.h>
#include <cstdint>

// ---------------------------------------------------------------------------
// BayesianNetwork: 2x vMF-normalized GEMM(1024x4096x4096) + relu, gaussian
// last layer [4096->5] + log_softmax, plus closed-form scalar terms.
// Split-bf16 GEMM (hi*hi+hi*lo+lo*hi) on the 2.5PF MFMA pipe.
// R9: m97 geometry -- 128x128 block, 4 waves, 64x64 wave tile, BK=32:
// 48 MFMA + 16 ds_read_b128 per wave-K-step (2x barrier amortization,
// 1.5x LDS efficiency vs R8's 32x64 wave tile). Split-K=2, R4 loop body.
// ---------------------------------------------------------------------------

#define NH (-0.9189385332046727)   // -0.5*log(2*pi)
#define DPI 3.141592653589793238462643383279502884

typedef short s16x8 __attribute__((ext_vector_type(8)));
typedef float f32x4 __attribute__((ext_vector_type(4)));

static __device__ __forceinline__ ushort f2bf(float f) {
  uint32_t u = __float_as_uint(f);
  u += 0x7fffu + ((u >> 16) & 1u);   // RNE
  return (ushort)(u >> 16);
}
static __device__ __forceinline__ float bf2f(ushort h) {
  return __uint_as_float(((uint32_t)h) << 16);
}

// global -> LDS direct copy, 16B per lane; LDS dest linear in lane id.
static __device__ __forceinline__ void gload16(const void* g, void* l) {
  __builtin_amdgcn_global_load_lds(
      (__attribute__((address_space(1))) void*)g,
      (__attribute__((address_space(3))) void*)l,
      16, 0, 0);
}

// --------------------------- small reductions (one launch) -----------------
// P layout (doubles): Pw1[8192]@0, Pw2[8192]@8192, Pb1[8]@16384, Pb2[8]@16392,
// Pw3[8]@16400, Pb3[1]@16408, Pr3[8]@16409, Pbr3[1]@16417
__global__ void small_reduce_k(const float* __restrict__ b1,
                               const float* __restrict__ b2,
                               const float* __restrict__ w3,
                               const float* __restrict__ b3,
                               const float* __restrict__ r3,
                               const float* __restrict__ br3,
                               double* __restrict__ P) {
  const int bid = blockIdx.x;
  const float* x; int n, lb, nb, mode; double* out;
  if (bid < 8)        { x = b1;  n = 4096;  lb = bid;      nb = 8; mode = 0; out = P + 16384; }
  else if (bid < 16)  { x = b2;  n = 4096;  lb = bid - 8;  nb = 8; mode = 0; out = P + 16392; }
  else if (bid < 24)  { x = w3;  n = 20480; lb = bid - 16; nb = 8; mode = 0; out = P + 16400; }
  else if (bid == 24) { x = b3;  n = 5;     lb = 0;        nb = 1; mode = 0; out = P + 16408; }
  else if (bid < 33)  { x = r3;  n = 20480; lb = bid - 25; nb = 8; mode = 1; out = P + 16409; }
  else                { x = br3; n = 5;     lb = 0;        nb = 1; mode = 1; out = P + 16417; }
  double a = 0.0;
  const int tid = lb * 256 + threadIdx.x, stride = nb * 256;
  for (int i = tid; i < n; i += stride) {
    float v = x[i];
    a += (mode == 0) ? (double)v * v : log(log1p(exp((double)v)));
  }
  for (int o = 32; o > 0; o >>= 1) a += __shfl_down(a, o);
  __shared__ double red[4];
  if ((threadIdx.x & 63) == 0) red[threadIdx.x >> 6] = a;
  __syncthreads();
  if (threadIdx.x == 0) out[lb] = red[0] + red[1] + red[2] + red[3];
}

// --------------------------- norm scalars ----------------------------------
__global__ void norms_k(const double* __restrict__ pw, int nw,
                        const double* __restrict__ pb, int nb,
                        float* __restrict__ out2) {
  __shared__ double red[4];
  const int t = threadIdx.x;
  double s[2];
  const double* p[2] = {pw, pb};
  const int   cn[2] = {nw, nb};
  for (int q = 0; q < 2; q++) {
    double v = 0.0;
    for (int i = t; i < cn[q]; i += 256) v += p[q][i];
    for (int o = 32; o > 0; o >>= 1) v += __shfl_down(v, o);
    if ((t & 63) == 0) red[t >> 6] = v;
    __syncthreads();
    s[q] = red[0] + red[1] + red[2] + red[3];
    __syncthreads();
  }
  if (t == 0) {
    out2[0] = (float)(1.0 / sqrt(s[0]));
    out2[1] = (float)(1.0 / sqrt(s[1]));
  }
}

// --------------------------- scalar finalize -------------------------------
static __device__ double logC_vmf(double d, double kappa) {
  double s  = 0.5 * d - 1.0;
  double x  = kappa / s;
  double sq = sqrt(1.0 + x * x);
  double eta = sq + log(x) - log1p(sq);
  double lb  = s * eta - 0.5 * log(2.0 * DPI * s) - 0.5 * log(sq);
  return d * NH + s * log(kappa) - lb;
}

__global__ void finalize_k(const double* __restrict__ P,
                           const float* lkw1, const float* lkb1,
                           const float* lkw2, const float* lkb2,
                           float* __restrict__ out_sc) {
  __shared__ double S[8];
  __shared__ double red[4];
  // S order: Sw1, Sb1, Sw2, Sb2, Sw3, Sb3, R6, R7
  const int offs[8] = {0, 16384, 8192, 16392, 16400, 16408, 16409, 16417};
  const int cnts[8] = {8192, 8, 8192, 8, 8, 1, 8, 1};
  const int t = threadIdx.x;
  for (int ai = 0; ai < 8; ai++) {
    double v = 0.0;
    for (int i = t; i < cnts[ai]; i += 256) v += P[offs[ai] + i];
    for (int o = 32; o > 0; o >>= 1) v += __shfl_down(v, o);
    if ((t & 63) == 0) red[t >> 6] = v;
    __syncthreads();
    if (t == 0) S[ai] = red[0] + red[1] + red[2] + red[3];
    __syncthreads();
  }
  if (t == 0) {
    double Sw3 = S[4], Sb3 = S[5], R6 = S[6], R7 = S[7];
    const double dw = 16777216.0, db = 4096.0;
    double kw1 = exp((double)lkw1[0]) + 1e-6;
    double kb1 = exp((double)lkb1[0]) + 1e-6;
    double kw2 = exp((double)lkw2[0]) + 1e-6;
    double kb2 = exp((double)lkb2[0]) + 1e-6;
    // dot(mu, mu) == 1 exactly (sumsq / norm^2)
    double lvp = kw1 + logC_vmf(dw, kw1) + kb1 + logC_vmf(db, kb1)
               + kw2 + logC_vmf(dw, kw2) + kb2 + logC_vmf(db, kb2)
               + 20485.0 * NH - R6 - R7;                 // gaussian layer lvp
    // reference: h stays f64 in h*log(pi); only gammaln's arg goes through f32
    double h64 = (dw + 1.0) * 0.5;                       // 8388608.5
    double hf  = (double)(float)h64;                     // 8388608.0
    double lsa = log(2.0) + h64 * log(DPI) - lgamma(hf);
    double lp  = -4.0 * lsa + 20485.0 * NH - 0.5 * (Sw3 + Sb3);
    out_sc[0] = (float)lvp;
    out_sc[1] = (float)lp;
  }
}

// --------------------------- bf16 hi/lo splitting --------------------------
__global__ void split_plain_k(const float* __restrict__ in,
                              ushort* __restrict__ hi, ushort* __restrict__ lo,
                              int n4) {
  int i = blockIdx.x * blockDim.x + threadIdx.x;
  if (i >= n4) return;
  float4 v = reinterpret_cast<const float4*>(in)[i];
  ushort4 h, l;
  h.x = f2bf(v.x); l.x = f2bf(v.x - bf2f(h.x));
  h.y = f2bf(v.y); l.y = f2bf(v.y - bf2f(h.y));
  h.z = f2bf(v.z); l.z = f2bf(v.z - bf2f(h.z));
  h.w = f2bf(v.w); l.w = f2bf(v.w - bf2f(h.w));
  reinterpret_cast<ushort4*>(hi)[i] = h;
  reinterpret_cast<ushort4*>(lo)[i] = l;
}

// W viewed [K=4096][N=4096] row-major -> WT hi/lo [N][K] (unscaled), plus
// per-block sum(x^2) partial (fused norm reduction).
__global__ void split_transpose_k(const float* __restrict__ in,
                                  ushort* __restrict__ hi,
                                  ushort* __restrict__ lo,
                                  double* __restrict__ part) {
  __shared__ float tile[64][33];
  __shared__ double red[4];
  const int tx = threadIdx.x, ty = threadIdx.y;  // (32,8)
  const int n0 = blockIdx.x * 32, k0 = blockIdx.y * 64;
  double a = 0.0;
#pragma unroll
  for (int r = 0; r < 8; r++) {
    float v = in[(size_t)(k0 + ty + r * 8) * 4096 + n0 + tx];
    tile[ty + r * 8][tx] = v;
    a += (double)v * v;
  }
  __syncthreads();
#pragma unroll
  for (int r = 0; r < 4; r++) {
    const int nn = ty + r * 8;
    float v0 = tile[2 * tx][nn];
    float v1 = tile[2 * tx + 1][nn];
    ushort2 h, l;
    h.x = f2bf(v0); l.x = f2bf(v0 - bf2f(h.x));
    h.y = f2bf(v1); l.y = f2bf(v1 - bf2f(h.y));
    size_t o = ((size_t)(n0 + nn) * 4096 + k0 + 2 * tx) >> 1;  // ushort2 index
    reinterpret_cast<ushort2*>(hi)[o] = h;
    reinterpret_cast<ushort2*>(lo)[o] = l;
  }
  const int tid = ty * 32 + tx;
  for (int o = 32; o > 0; o >>= 1) a += __shfl_down(a, o);
  if ((tid & 63) == 0) red[tid >> 6] = a;
  __syncthreads();
  if (tid == 0)
    part[blockIdx.y * gridDim.x + blockIdx.x] = red[0] + red[1] + red[2] + red[3];
}

// --------------------------- split-bf16 GEMM -------------------------------
// C[128x128]/block, BK=32, 4 waves (2x2, wave tile 64x64), 3 MFMAs per pair.
// Per wave-K-step: 16 ds_read_b128 + 48 MFMA (m97 geometry + hi/lo variants).
// R4-proven loop: STAGE -> barrier -> COMPUTE -> barrier (single LDS buffer).
// Each block covers K range [z*ksize, (z+1)*ksize).
// mode 0: relu(acc*wsc+bias*bsc) -> hi/lo bf16. mode 1: same -> f32.
// mode 2: raw f32 partial to Of + z*M*N (split-K; combine applies epilogue).
__global__ __launch_bounds__(256) void gemm_split_k(
    const ushort* __restrict__ Ahi, const ushort* __restrict__ Alo,
    const ushort* __restrict__ Bhi, const ushort* __restrict__ Blo,
    const float* __restrict__ bias, const float* __restrict__ scales,
    ushort* __restrict__ Ohi, ushort* __restrict__ Olo,
    float* __restrict__ Of,
    int M, int N, int K, int ksize, int mode) {
  __shared__ ushort As[2][128 * 32];   // [hi/lo]
  __shared__ ushort Bs[2][128 * 32];   // 32 KB total
  const int t = threadIdx.x;
  const int lane = t & 63, wid = t >> 6;
  const int wm = wid >> 1, wn = wid & 1;
  const int bm = blockIdx.y, bn = blockIdx.x;
  const int lr = lane & 15, lk = (lane >> 4) * 8;

  f32x4 acc[4][4];
#pragma unroll
  for (int i = 0; i < 4; i++)
#pragma unroll
    for (int j = 0; j < 4; j++) acc[i][j] = (f32x4){0.f, 0.f, 0.f, 0.f};

  const size_t arow = (size_t)(bm * 128) * K;
  const size_t brow = (size_t)(bn * 128) * K;
  const int kbeg = blockIdx.z * ksize;
  const int kend = kbeg + ksize;

  for (int k0 = kbeg; k0 < kend; k0 += 32) {
#pragma unroll
    for (int q = 0; q < 2; q++) {
      const int L = q * 256 + t;
      const int row = L >> 2, ch = (L & 3) * 8;   // 128 rows x 4 chunks
      const size_t ga = arow + (size_t)row * K + k0 + ch;
      const size_t gb = brow + (size_t)row * K + k0 + ch;
      gload16(Ahi + ga, &As[0][L * 8]);
      gload16(Alo + ga, &As[1][L * 8]);
      gload16(Bhi + gb, &Bs[0][L * 8]);
      gload16(Blo + gb, &Bs[1][L * 8]);
    }
    __syncthreads();
    s16x8 ah[4], al[4], bh[4], bl[4];
#pragma unroll
    for (int i = 0; i < 4; i++) {
      const int ra = (wm * 64 + i * 16 + lr) * 32 + lk;
      ah[i] = *(const s16x8*)&As[0][ra];
      al[i] = *(const s16x8*)&As[1][ra];
    }
#pragma unroll
    for (int j = 0; j < 4; j++) {
      const int rb = (wn * 64 + j * 16 + lr) * 32 + lk;
      bh[j] = *(const s16x8*)&Bs[0][rb];
      bl[j] = *(const s16x8*)&Bs[1][rb];
    }
#pragma unroll
    for (int i = 0; i < 4; i++)
#pragma unroll
      for (int j = 0; j < 4; j++) {
        acc[i][j] = __builtin_amdgcn_mfma_f32_16x16x32_bf16(ah[i], bh[j], acc[i][j], 0, 0, 0);
        acc[i][j] = __builtin_amdgcn_mfma_f32_16x16x32_bf16(ah[i], bl[j], acc[i][j], 0, 0, 0);
        acc[i][j] = __builtin_amdgcn_mfma_f32_16x16x32_bf16(al[i], bh[j], acc[i][j], 0, 0, 0);
      }
    __syncthreads();
  }

  const int rb0 = bm * 128 + wm * 64 + (lane >> 4) * 4;
  const int cb0 = bn * 128 + wn * 64 + lr;
  if (mode == 2) {
    float* Op = Of + (size_t)blockIdx.z * ((size_t)M * N);
#pragma unroll
    for (int j = 0; j < 4; j++) {
      const int col = cb0 + j * 16;
#pragma unroll
      for (int i = 0; i < 4; i++)
#pragma unroll
        for (int r = 0; r < 4; r++)
          Op[(size_t)(rb0 + i * 16 + r) * N + col] = acc[i][j][r];
    }
    return;
  }
  const float wsc = scales[0], bsc = scales[1];
#pragma unroll
  for (int j = 0; j < 4; j++) {
    const int col = cb0 + j * 16;
    const float bv = bias[col] * bsc;
#pragma unroll
    for (int i = 0; i < 4; i++) {
#pragma unroll
      for (int r = 0; r < 4; r++) {
        const int row = rb0 + i * 16 + r;
        float v = fmaxf(fmaf(acc[i][j][r], wsc, bv), 0.0f);
        const size_t o = (size_t)row * N + col;
        if (mode == 0) {
          ushort h = f2bf(v);
          Ohi[o] = h;
          Olo[o] = f2bf(v - bf2f(h));
        } else {
          Of[o] = v;
        }
      }
    }
  }
}

// --------------------------- split-K combine + epilogue --------------------
// v = relu((p0+p1)*wsc + bias*bsc); mode 0 -> hi/lo bf16, mode 1 -> f32.
__global__ void combine_k(const float* __restrict__ p,
                          const float* __restrict__ bias,
                          const float* __restrict__ sc,
                          ushort* __restrict__ Ohi, ushort* __restrict__ Olo,
                          float* __restrict__ Of, int mode) {
  const int i = blockIdx.x * blockDim.x + threadIdx.x;   // float4 index, 1M
  const float wsc = sc[0], bsc = sc[1];
  float4 a = reinterpret_cast<const float4*>(p)[i];
  float4 b = reinterpret_cast<const float4*>(p + 4194304)[i];
  float4 bv = *reinterpret_cast<const float4*>(bias + ((i * 4) & 4095));
  float4 v;
  v.x = fmaxf(fmaf(a.x + b.x, wsc, bv.x * bsc), 0.f);
  v.y = fmaxf(fmaf(a.y + b.y, wsc, bv.y * bsc), 0.f);
  v.z = fmaxf(fmaf(a.z + b.z, wsc, bv.z * bsc), 0.f);
  v.w = fmaxf(fmaf(a.w + b.w, wsc, bv.w * bsc), 0.f);
  if (mode == 0) {
    ushort4 h, l;
    h.x = f2bf(v.x); l.x = f2bf(v.x - bf2f(h.x));
    h.y = f2bf(v.y); l.y = f2bf(v.y - bf2f(h.y));
    h.z = f2bf(v.z); l.z = f2bf(v.z - bf2f(h.z));
    h.w = f2bf(v.w); l.w = f2bf(v.w - bf2f(h.w));
    reinterpret_cast<ushort4*>(Ohi)[i] = h;
    reinterpret_cast<ushort4*>(Olo)[i] = l;
  } else {
    reinterpret_cast<float4*>(Of)[i] = v;
  }
}

// --------------------------- last layer + log_softmax ----------------------
__global__ void layer3_k(const float* __restrict__ h2,
                         const float* __restrict__ w3,
                         const float* __restrict__ b3,
                         float* __restrict__ out) {
  const int row = blockIdx.x;
  const int t = threadIdx.x;
  const float* hr = h2 + (size_t)row * 4096;
  float a[5] = {0.f, 0.f, 0.f, 0.f, 0.f};
  for (int k = t; k < 4096; k += 256) {
    const float h = hr[k];
#pragma unroll
    for (int o = 0; o < 5; o++) a[o] += h * w3[o * 4096 + k];
  }
#pragma unroll
  for (int o = 0; o < 5; o++)
    for (int s = 32; s > 0; s >>= 1) a[o] += __shfl_down(a[o], s);
  __shared__ float red[4][5];
  if ((t & 63) == 0) {
#pragma unroll
    for (int o = 0; o < 5; o++) red[t >> 6][o] = a[o];
  }
  __syncthreads();
  if (t == 0) {
    float y[5];
#pragma unroll
    for (int o = 0; o < 5; o++)
      y[o] = red[0][o] + red[1][o] + red[2][o] + red[3][o] + b3[o];
    float m = y[0];
    for (int o = 1; o < 5; o++) m = fmaxf(m, y[o]);
    float ssum = 0.f;
    for (int o = 0; o < 5; o++) ssum += expf(y[o] - m);
    const float ls = m + logf(ssum);
    for (int o = 0; o < 5; o++) out[row * 5 + o] = y[o] - ls;
  }
}

// --------------------------- launcher --------------------------------------
extern "C" void kernel_launch(void* const* d_in, const int* in_sizes, int n_in,
                              void* d_out, int out_size, void* d_ws, size_t ws_size,
                              hipStream_t stream) {
  const float* x     = (const float*)d_in[0];
  const float* w1mu  = (const float*)d_in[1];
  const float* lkw1  = (const float*)d_in[2];
  const float* b1mu  = (const float*)d_in[3];
  const float* lkb1  = (const float*)d_in[4];
  const float* w2mu  = (const float*)d_in[5];
  const float* lkw2  = (const float*)d_in[6];
  const float* b2mu  = (const float*)d_in[7];
  const float* lkb2  = (const float*)d_in[8];
  const float* w3mu  = (const float*)d_in[9];
  const float* w3rho = (const float*)d_in[10];
  const float* b3mu  = (const float*)d_in[11];
  const float* b3rho = (const float*)d_in[12];
  float* outp = (float*)d_out;

  // workspace layout: 256KB header + 32MB x/h1 + 64MB wt (+32MB partials)
  char* w = (char*)d_ws;
  double* P    = (double*)w;          // partials, 16418 doubles (~131 KB)
  double* Pw1  = P;                   // 8192
  double* Pw2  = P + 8192;            // 8192
  float* params = (float*)(w + 140 * 1024);               // [0..3]
  ushort* xhi  = (ushort*)(w + 256 * 1024);               // 1024x4096 bf16
  ushort* xlo  = xhi  + (size_t)1024 * 4096;
  ushort* h1hi = xlo  + (size_t)1024 * 4096;
  ushort* h1lo = h1hi + (size_t)1024 * 4096;
  ushort* wthi = (ushort*)(h1lo + (size_t)1024 * 4096);   // 4096x4096 bf16
  ushort* wtlo = wthi + (size_t)4096 * 4096;
  float*  part = (float*)(wtlo + (size_t)4096 * 4096);    // 2 x 16MB f32
  float*  h2   = (float*)xhi;   // reuse x hi/lo region (dead after GEMM1)

  // split-K=2 needs 128.3MB of ws; fall back deterministically otherwise.
  const bool splitk = ws_size >= (size_t)134479872;

  split_plain_k<<<4096, 256, 0, stream>>>(x, xhi, xlo, 1048576);
  split_transpose_k<<<dim3(128, 64), dim3(32, 8), 0, stream>>>(w1mu, wthi, wtlo, Pw1);
  small_reduce_k<<<34, 256, 0, stream>>>(b1mu, b2mu, w3mu, b3mu, w3rho, b3rho, P);
  norms_k<<<1, 256, 0, stream>>>(Pw1, 8192, P + 16384, 8, params + 0);
  // layer 1: h1 = relu((x @ W1n) + b1n) -> bf16 hi/lo
  if (splitk) {
    gemm_split_k<<<dim3(32, 8, 2), 256, 0, stream>>>(
        xhi, xlo, wthi, wtlo, nullptr, nullptr, nullptr, nullptr, part,
        1024, 4096, 4096, 2048, 2);
    combine_k<<<4096, 256, 0, stream>>>(part, b1mu, params + 0,
                                        h1hi, h1lo, nullptr, 0);
  } else {
    gemm_split_k<<<dim3(32, 8, 1), 256, 0, stream>>>(
        xhi, xlo, wthi, wtlo, b1mu, params + 0, h1hi, h1lo, nullptr,
        1024, 4096, 4096, 4096, 0);
  }
  // layer 2 prep + GEMM -> f32 h2
  split_transpose_k<<<dim3(128, 64), dim3(32, 8), 0, stream>>>(w2mu, wthi, wtlo, Pw2);
  norms_k<<<1, 256, 0, stream>>>(Pw2, 8192, P + 16392, 8, params + 2);
  if (splitk) {
    gemm_split_k<<<dim3(32, 8, 2), 256, 0, stream>>>(
        h1hi, h1lo, wthi, wtlo, nullptr, nullptr, nullptr, nullptr, part,
        1024, 4096, 4096, 2048, 2);
    combine_k<<<4096, 256, 0, stream>>>(part, b2mu, params + 2,
                                        nullptr, nullptr, h2, 1);
  } else {
    gemm_split_k<<<dim3(32, 8, 1), 256, 0, stream>>>(
        h1hi, h1lo, wthi, wtlo, b2mu, params + 2, nullptr, nullptr, h2,
        1024, 4096, 4096, 4096, 1);
  }
  // scalars + last layer
  finalize_k<<<1, 256, 0, stream>>>(P, lkw1, lkb1, lkw2, lkb2, outp + 5120);
  layer3_k<<<1024, 256, 0, stream>>>(h2, w3mu, b3mu, outp);
}

// Round 11
// 454.794 us; speedup vs baseline: 1.2497x; 1.0456x over previous
//
#include <hip/hip_runtime.h>
#include <cstdint>

// ---------------------------------------------------------------------------
// BayesianNetwork: 2x vMF-normalized GEMM(1024x4096x4096) + relu, gaussian
// last layer [4096->5] + log_softmax, plus closed-form scalar terms.
// Split-bf16 GEMM (hi*hi+hi*lo+lo*hi) on the 2.5PF MFMA pipe.
// R11: GEMM unchanged from R10 (930 TF MFMA rate = m97-structure ceiling).
// split_transpose vectorized: float4 reads + ushort4 writes via 64x64 LDS
// tile (pad 69 -> conflict-free); layer3 float4 loads.
// ---------------------------------------------------------------------------

#define NH (-0.9189385332046727)   // -0.5*log(2*pi)
#define DPI 3.141592653589793238462643383279502884

typedef short s16x8 __attribute__((ext_vector_type(8)));
typedef float f32x4 __attribute__((ext_vector_type(4)));

static __device__ __forceinline__ ushort f2bf(float f) {
  uint32_t u = __float_as_uint(f);
  u += 0x7fffu + ((u >> 16) & 1u);   // RNE
  return (ushort)(u >> 16);
}
static __device__ __forceinline__ float bf2f(ushort h) {
  return __uint_as_float(((uint32_t)h) << 16);
}

// global -> LDS direct copy, 16B per lane; LDS dest linear in lane id.
static __device__ __forceinline__ void gload16(const void* g, void* l) {
  __builtin_amdgcn_global_load_lds(
      (__attribute__((address_space(1))) void*)g,
      (__attribute__((address_space(3))) void*)l,
      16, 0, 0);
}

// --------------------------- small reductions (one launch) -----------------
// P layout (doubles): Pw1[4096]@0, Pw2[4096]@8192, Pb1[8]@16384, Pb2[8]@16392,
// Pw3[8]@16400, Pb3[1]@16408, Pr3[8]@16409, Pbr3[1]@16417
__global__ void small_reduce_k(const float* __restrict__ b1,
                               const float* __restrict__ b2,
                               const float* __restrict__ w3,
                               const float* __restrict__ b3,
                               const float* __restrict__ r3,
                               const float* __restrict__ br3,
                               double* __restrict__ P) {
  const int bid = blockIdx.x;
  const float* x; int n, lb, nb, mode; double* out;
  if (bid < 8)        { x = b1;  n = 4096;  lb = bid;      nb = 8; mode = 0; out = P + 16384; }
  else if (bid < 16)  { x = b2;  n = 4096;  lb = bid - 8;  nb = 8; mode = 0; out = P + 16392; }
  else if (bid < 24)  { x = w3;  n = 20480; lb = bid - 16; nb = 8; mode = 0; out = P + 16400; }
  else if (bid == 24) { x = b3;  n = 5;     lb = 0;        nb = 1; mode = 0; out = P + 16408; }
  else if (bid < 33)  { x = r3;  n = 20480; lb = bid - 25; nb = 8; mode = 1; out = P + 16409; }
  else                { x = br3; n = 5;     lb = 0;        nb = 1; mode = 1; out = P + 16417; }
  double a = 0.0;
  const int tid = lb * 256 + threadIdx.x, stride = nb * 256;
  for (int i = tid; i < n; i += stride) {
    float v = x[i];
    a += (mode == 0) ? (double)v * v : log(log1p(exp((double)v)));
  }
  for (int o = 32; o > 0; o >>= 1) a += __shfl_down(a, o);
  __shared__ double red[4];
  if ((threadIdx.x & 63) == 0) red[threadIdx.x >> 6] = a;
  __syncthreads();
  if (threadIdx.x == 0) out[lb] = red[0] + red[1] + red[2] + red[3];
}

// --------------------------- norm scalars ----------------------------------
__global__ void norms_k(const double* __restrict__ pw, int nw,
                        const double* __restrict__ pb, int nb,
                        float* __restrict__ out2) {
  __shared__ double red[4];
  const int t = threadIdx.x;
  double s[2];
  const double* p[2] = {pw, pb};
  const int   cn[2] = {nw, nb};
  for (int q = 0; q < 2; q++) {
    double v = 0.0;
    for (int i = t; i < cn[q]; i += 256) v += p[q][i];
    for (int o = 32; o > 0; o >>= 1) v += __shfl_down(v, o);
    if ((t & 63) == 0) red[t >> 6] = v;
    __syncthreads();
    s[q] = red[0] + red[1] + red[2] + red[3];
    __syncthreads();
  }
  if (t == 0) {
    out2[0] = (float)(1.0 / sqrt(s[0]));
    out2[1] = (float)(1.0 / sqrt(s[1]));
  }
}

// --------------------------- scalar finalize -------------------------------
static __device__ double logC_vmf(double d, double kappa) {
  double s  = 0.5 * d - 1.0;
  double x  = kappa / s;
  double sq = sqrt(1.0 + x * x);
  double eta = sq + log(x) - log1p(sq);
  double lb  = s * eta - 0.5 * log(2.0 * DPI * s) - 0.5 * log(sq);
  return d * NH + s * log(kappa) - lb;
}

__global__ void finalize_k(const double* __restrict__ P,
                           const float* lkw1, const float* lkb1,
                           const float* lkw2, const float* lkb2,
                           float* __restrict__ out_sc) {
  __shared__ double S[8];
  __shared__ double red[4];
  // S order: Sw1, Sb1, Sw2, Sb2, Sw3, Sb3, R6, R7
  const int offs[8] = {0, 16384, 8192, 16392, 16400, 16408, 16409, 16417};
  const int cnts[8] = {4096, 8, 4096, 8, 8, 1, 8, 1};
  const int t = threadIdx.x;
  for (int ai = 0; ai < 8; ai++) {
    double v = 0.0;
    for (int i = t; i < cnts[ai]; i += 256) v += P[offs[ai] + i];
    for (int o = 32; o > 0; o >>= 1) v += __shfl_down(v, o);
    if ((t & 63) == 0) red[t >> 6] = v;
    __syncthreads();
    if (t == 0) S[ai] = red[0] + red[1] + red[2] + red[3];
    __syncthreads();
  }
  if (t == 0) {
    double Sw3 = S[4], Sb3 = S[5], R6 = S[6], R7 = S[7];
    const double dw = 16777216.0, db = 4096.0;
    double kw1 = exp((double)lkw1[0]) + 1e-6;
    double kb1 = exp((double)lkb1[0]) + 1e-6;
    double kw2 = exp((double)lkw2[0]) + 1e-6;
    double kb2 = exp((double)lkb2[0]) + 1e-6;
    // dot(mu, mu) == 1 exactly (sumsq / norm^2)
    double lvp = kw1 + logC_vmf(dw, kw1) + kb1 + logC_vmf(db, kb1)
               + kw2 + logC_vmf(dw, kw2) + kb2 + logC_vmf(db, kb2)
               + 20485.0 * NH - R6 - R7;                 // gaussian layer lvp
    // reference: h stays f64 in h*log(pi); only gammaln's arg goes through f32
    double h64 = (dw + 1.0) * 0.5;                       // 8388608.5
    double hf  = (double)(float)h64;                     // 8388608.0
    double lsa = log(2.0) + h64 * log(DPI) - lgamma(hf);
    double lp  = -4.0 * lsa + 20485.0 * NH - 0.5 * (Sw3 + Sb3);
    out_sc[0] = (float)lvp;
    out_sc[1] = (float)lp;
  }
}

// --------------------------- bf16 hi/lo splitting --------------------------
__global__ void split_plain_k(const float* __restrict__ in,
                              ushort* __restrict__ hi, ushort* __restrict__ lo,
                              int n4) {
  int i = blockIdx.x * blockDim.x + threadIdx.x;
  if (i >= n4) return;
  float4 v = reinterpret_cast<const float4*>(in)[i];
  ushort4 h, l;
  h.x = f2bf(v.x); l.x = f2bf(v.x - bf2f(h.x));
  h.y = f2bf(v.y); l.y = f2bf(v.y - bf2f(h.y));
  h.z = f2bf(v.z); l.z = f2bf(v.z - bf2f(h.z));
  h.w = f2bf(v.w); l.w = f2bf(v.w - bf2f(h.w));
  reinterpret_cast<ushort4*>(hi)[i] = h;
  reinterpret_cast<ushort4*>(lo)[i] = l;
}

// W viewed [K=4096][N=4096] row-major -> WT hi/lo [N][K] (unscaled), plus
// per-block sum(x^2) partial. 64x64 tile; float4 reads (16B/lane), LDS
// [64][69] (pad 69 -> 2-way aliasing only), ushort4 writes (8B/lane).
__global__ void split_transpose_k(const float* __restrict__ in,
                                  ushort* __restrict__ hi,
                                  ushort* __restrict__ lo,
                                  double* __restrict__ part) {
  __shared__ float tile[64][69];
  __shared__ double red[4];
  const int t = threadIdx.x;                       // 256
  const int n0 = blockIdx.x * 64, k0 = blockIdx.y * 64;
  double a = 0.0;
#pragma unroll
  for (int r = 0; r < 4; r++) {
    const int idx = r * 256 + t;
    const int row = idx >> 4, c4 = (idx & 15) * 4;  // k-row, n-col quad
    float4 v = *reinterpret_cast<const float4*>(
        &in[(size_t)(k0 + row) * 4096 + n0 + c4]);
    tile[row][c4 + 0] = v.x; tile[row][c4 + 1] = v.y;
    tile[row][c4 + 2] = v.z; tile[row][c4 + 3] = v.w;
    a += (double)v.x * v.x + (double)v.y * v.y
       + (double)v.z * v.z + (double)v.w * v.w;
  }
  __syncthreads();
#pragma unroll
  for (int r = 0; r < 4; r++) {
    const int idx = r * 256 + t;
    const int nn = idx >> 4, kc = (idx & 15) * 4;   // n-row, k-col quad
    const float v0 = tile[kc + 0][nn], v1 = tile[kc + 1][nn];
    const float v2 = tile[kc + 2][nn], v3 = tile[kc + 3][nn];
    ushort4 h, l;
    h.x = f2bf(v0); l.x = f2bf(v0 - bf2f(h.x));
    h.y = f2bf(v1); l.y = f2bf(v1 - bf2f(h.y));
    h.z = f2bf(v2); l.z = f2bf(v2 - bf2f(h.z));
    h.w = f2bf(v3); l.w = f2bf(v3 - bf2f(h.w));
    const size_t o = ((size_t)(n0 + nn) * 4096 + k0 + kc) >> 2;  // ushort4 idx
    reinterpret_cast<ushort4*>(hi)[o] = h;
    reinterpret_cast<ushort4*>(lo)[o] = l;
  }
  for (int o = 32; o > 0; o >>= 1) a += __shfl_down(a, o);
  if ((t & 63) == 0) red[t >> 6] = a;
  __syncthreads();
  if (t == 0)
    part[blockIdx.y * gridDim.x + blockIdx.x] = red[0] + red[1] + red[2] + red[3];
}

// --------------------------- split-bf16 GEMM -------------------------------
// C[128x128]/block, BK=32, 4 waves (2x2, wave tile 64x64), 3 MFMAs per pair.
// Per wave-K-step: 16 ds_read_b128 + 48 MFMA (m97 geometry; 930 TF measured).
// R4-proven loop: STAGE -> barrier -> COMPUTE -> barrier (single LDS buffer).
// mode 0: relu(acc*wsc+bias*bsc) -> hi/lo bf16. mode 1: same -> f32.
// mode 2: raw f32 partial to Of + z*M*N (split-K; combine applies epilogue).
__global__ __launch_bounds__(256) void gemm_split_k(
    const ushort* __restrict__ Ahi, const ushort* __restrict__ Alo,
    const ushort* __restrict__ Bhi, const ushort* __restrict__ Blo,
    const float* __restrict__ bias, const float* __restrict__ scales,
    ushort* __restrict__ Ohi, ushort* __restrict__ Olo,
    float* __restrict__ Of,
    int M, int N, int K, int ksize, int mode) {
  __shared__ ushort As[2][128 * 32];   // [hi/lo]
  __shared__ ushort Bs[2][128 * 32];   // 32 KB total
  const int t = threadIdx.x;
  const int lane = t & 63, wid = t >> 6;
  const int wm = wid >> 1, wn = wid & 1;
  const int bm = blockIdx.y, bn = blockIdx.x;
  const int lr = lane & 15, lk = (lane >> 4) * 8;

  f32x4 acc[4][4];
#pragma unroll
  for (int i = 0; i < 4; i++)
#pragma unroll
    for (int j = 0; j < 4; j++) acc[i][j] = (f32x4){0.f, 0.f, 0.f, 0.f};

  const size_t arow = (size_t)(bm * 128) * K;
  const size_t brow = (size_t)(bn * 128) * K;
  const int kbeg = blockIdx.z * ksize;
  const int kend = kbeg + ksize;

  for (int k0 = kbeg; k0 < kend; k0 += 32) {
#pragma unroll
    for (int q = 0; q < 2; q++) {
      const int L = q * 256 + t;
      const int row = L >> 2, ch = (L & 3) * 8;   // 128 rows x 4 chunks
      const size_t ga = arow + (size_t)row * K + k0 + ch;
      const size_t gb = brow + (size_t)row * K + k0 + ch;
      gload16(Ahi + ga, &As[0][L * 8]);
      gload16(Alo + ga, &As[1][L * 8]);
      gload16(Bhi + gb, &Bs[0][L * 8]);
      gload16(Blo + gb, &Bs[1][L * 8]);
    }
    __syncthreads();
    s16x8 ah[4], al[4], bh[4], bl[4];
#pragma unroll
    for (int i = 0; i < 4; i++) {
      const int ra = (wm * 64 + i * 16 + lr) * 32 + lk;
      ah[i] = *(const s16x8*)&As[0][ra];
      al[i] = *(const s16x8*)&As[1][ra];
    }
#pragma unroll
    for (int j = 0; j < 4; j++) {
      const int rb = (wn * 64 + j * 16 + lr) * 32 + lk;
      bh[j] = *(const s16x8*)&Bs[0][rb];
      bl[j] = *(const s16x8*)&Bs[1][rb];
    }
#pragma unroll
    for (int i = 0; i < 4; i++)
#pragma unroll
      for (int j = 0; j < 4; j++) {
        acc[i][j] = __builtin_amdgcn_mfma_f32_16x16x32_bf16(ah[i], bh[j], acc[i][j], 0, 0, 0);
        acc[i][j] = __builtin_amdgcn_mfma_f32_16x16x32_bf16(ah[i], bl[j], acc[i][j], 0, 0, 0);
        acc[i][j] = __builtin_amdgcn_mfma_f32_16x16x32_bf16(al[i], bh[j], acc[i][j], 0, 0, 0);
      }
    __syncthreads();
  }

  const int rb0 = bm * 128 + wm * 64 + (lane >> 4) * 4;
  const int cb0 = bn * 128 + wn * 64 + lr;
  if (mode == 2) {
    float* Op = Of + (size_t)blockIdx.z * ((size_t)M * N);
#pragma unroll
    for (int j = 0; j < 4; j++) {
      const int col = cb0 + j * 16;
#pragma unroll
      for (int i = 0; i < 4; i++)
#pragma unroll
        for (int r = 0; r < 4; r++)
          Op[(size_t)(rb0 + i * 16 + r) * N + col] = acc[i][j][r];
    }
    return;
  }
  const float wsc = scales[0], bsc = scales[1];
#pragma unroll
  for (int j = 0; j < 4; j++) {
    const int col = cb0 + j * 16;
    const float bv = bias[col] * bsc;
#pragma unroll
    for (int i = 0; i < 4; i++) {
#pragma unroll
      for (int r = 0; r < 4; r++) {
        const int row = rb0 + i * 16 + r;
        float v = fmaxf(fmaf(acc[i][j][r], wsc, bv), 0.0f);
        const size_t o = (size_t)row * N + col;
        if (mode == 0) {
          ushort h = f2bf(v);
          Ohi[o] = h;
          Olo[o] = f2bf(v - bf2f(h));
        } else {
          Of[o] = v;
        }
      }
    }
  }
}

// --------------------------- split-K combine + epilogue --------------------
// v = relu((p0+p1)*wsc + bias*bsc); mode 0 -> hi/lo bf16, mode 1 -> f32.
__global__ void combine_k(const float* __restrict__ p,
                          const float* __restrict__ bias,
                          const float* __restrict__ sc,
                          ushort* __restrict__ Ohi, ushort* __restrict__ Olo,
                          float* __restrict__ Of, int mode) {
  const int i = blockIdx.x * blockDim.x + threadIdx.x;   // float4 index, 1M
  const float wsc = sc[0], bsc = sc[1];
  float4 a = reinterpret_cast<const float4*>(p)[i];
  float4 b = reinterpret_cast<const float4*>(p + 4194304)[i];
  float4 bv = *reinterpret_cast<const float4*>(bias + ((i * 4) & 4095));
  float4 v;
  v.x = fmaxf(fmaf(a.x + b.x, wsc, bv.x * bsc), 0.f);
  v.y = fmaxf(fmaf(a.y + b.y, wsc, bv.y * bsc), 0.f);
  v.z = fmaxf(fmaf(a.z + b.z, wsc, bv.z * bsc), 0.f);
  v.w = fmaxf(fmaf(a.w + b.w, wsc, bv.w * bsc), 0.f);
  if (mode == 0) {
    ushort4 h, l;
    h.x = f2bf(v.x); l.x = f2bf(v.x - bf2f(h.x));
    h.y = f2bf(v.y); l.y = f2bf(v.y - bf2f(h.y));
    h.z = f2bf(v.z); l.z = f2bf(v.z - bf2f(h.z));
    h.w = f2bf(v.w); l.w = f2bf(v.w - bf2f(h.w));
    reinterpret_cast<ushort4*>(Ohi)[i] = h;
    reinterpret_cast<ushort4*>(Olo)[i] = l;
  } else {
    reinterpret_cast<float4*>(Of)[i] = v;
  }
}

// --------------------------- last layer + log_softmax ----------------------
__global__ void layer3_k(const float* __restrict__ h2,
                         const float* __restrict__ w3,
                         const float* __restrict__ b3,
                         float* __restrict__ out) {
  const int row = blockIdx.x;
  const int t = threadIdx.x;
  const float* hr = h2 + (size_t)row * 4096;
  float a[5] = {0.f, 0.f, 0.f, 0.f, 0.f};
  for (int k4 = t; k4 < 1024; k4 += 256) {
    const float4 hv = reinterpret_cast<const float4*>(hr)[k4];
#pragma unroll
    for (int o = 0; o < 5; o++) {
      const float4 wv = reinterpret_cast<const float4*>(w3)[o * 1024 + k4];
      a[o] += hv.x * wv.x + hv.y * wv.y + hv.z * wv.z + hv.w * wv.w;
    }
  }
#pragma unroll
  for (int o = 0; o < 5; o++)
    for (int s = 32; s > 0; s >>= 1) a[o] += __shfl_down(a[o], s);
  __shared__ float red[4][5];
  if ((t & 63) == 0) {
#pragma unroll
    for (int o = 0; o < 5; o++) red[t >> 6][o] = a[o];
  }
  __syncthreads();
  if (t == 0) {
    float y[5];
#pragma unroll
    for (int o = 0; o < 5; o++)
      y[o] = red[0][o] + red[1][o] + red[2][o] + red[3][o] + b3[o];
    float m = y[0];
    for (int o = 1; o < 5; o++) m = fmaxf(m, y[o]);
    float ssum = 0.f;
    for (int o = 0; o < 5; o++) ssum += expf(y[o] - m);
    const float ls = m + logf(ssum);
    for (int o = 0; o < 5; o++) out[row * 5 + o] = y[o] - ls;
  }
}

// --------------------------- launcher --------------------------------------
extern "C" void kernel_launch(void* const* d_in, const int* in_sizes, int n_in,
                              void* d_out, int out_size, void* d_ws, size_t ws_size,
                              hipStream_t stream) {
  const float* x     = (const float*)d_in[0];
  const float* w1mu  = (const float*)d_in[1];
  const float* lkw1  = (const float*)d_in[2];
  const float* b1mu  = (const float*)d_in[3];
  const float* lkb1  = (const float*)d_in[4];
  const float* w2mu  = (const float*)d_in[5];
  const float* lkw2  = (const float*)d_in[6];
  const float* b2mu  = (const float*)d_in[7];
  const float* lkb2  = (const float*)d_in[8];
  const float* w3mu  = (const float*)d_in[9];
  const float* w3rho = (const float*)d_in[10];
  const float* b3mu  = (const float*)d_in[11];
  const float* b3rho = (const float*)d_in[12];
  float* outp = (float*)d_out;

  // workspace layout: 256KB header + 32MB x/h1 + 64MB wt (+32MB partials)
  char* w = (char*)d_ws;
  double* P    = (double*)w;          // partials (~131 KB)
  double* Pw1  = P;                   // 4096
  double* Pw2  = P + 8192;            // 4096
  float* params = (float*)(w + 140 * 1024);               // [0..3]
  ushort* xhi  = (ushort*)(w + 256 * 1024);               // 1024x4096 bf16
  ushort* xlo  = xhi  + (size_t)1024 * 4096;
  ushort* h1hi = xlo  + (size_t)1024 * 4096;
  ushort* h1lo = h1hi + (size_t)1024 * 4096;
  ushort* wthi = (ushort*)(h1lo + (size_t)1024 * 4096);   // 4096x4096 bf16
  ushort* wtlo = wthi + (size_t)4096 * 4096;
  float*  part = (float*)(wtlo + (size_t)4096 * 4096);    // 2 x 16MB f32
  float*  h2   = (float*)xhi;   // reuse x hi/lo region (dead after GEMM1)

  // split-K=2 needs 128.3MB of ws; fall back deterministically otherwise.
  const bool splitk = ws_size >= (size_t)134479872;

  split_plain_k<<<4096, 256, 0, stream>>>(x, xhi, xlo, 1048576);
  split_transpose_k<<<dim3(64, 64), 256, 0, stream>>>(w1mu, wthi, wtlo, Pw1);
  small_reduce_k<<<34, 256, 0, stream>>>(b1mu, b2mu, w3mu, b3mu, w3rho, b3rho, P);
  norms_k<<<1, 256, 0, stream>>>(Pw1, 4096, P + 16384, 8, params + 0);
  // layer 1: h1 = relu((x @ W1n) + b1n) -> bf16 hi/lo
  if (splitk) {
    gemm_split_k<<<dim3(32, 8, 2), 256, 0, stream>>>(
        xhi, xlo, wthi, wtlo, nullptr, nullptr, nullptr, nullptr, part,
        1024, 4096, 4096, 2048, 2);
    combine_k<<<4096, 256, 0, stream>>>(part, b1mu, params + 0,
                                        h1hi, h1lo, nullptr, 0);
  } else {
    gemm_split_k<<<dim3(32, 8, 1), 256, 0, stream>>>(
        xhi, xlo, wthi, wtlo, b1mu, params + 0, h1hi, h1lo, nullptr,
        1024, 4096, 4096, 4096, 0);
  }
  // layer 2 prep + GEMM -> f32 h2
  split_transpose_k<<<dim3(64, 64), 256, 0, stream>>>(w2mu, wthi, wtlo, Pw2);
  norms_k<<<1, 256, 0, stream>>>(Pw2, 4096, P + 16392, 8, params + 2);
  if (splitk) {
    gemm_split_k<<<dim3(32, 8, 2), 256, 0, stream>>>(
        h1hi, h1lo, wthi, wtlo, nullptr, nullptr, nullptr, nullptr, part,
        1024, 4096, 4096, 2048, 2);
    combine_k<<<4096, 256, 0, stream>>>(part, b2mu, params + 2,
                                        nullptr, nullptr, h2, 1);
  } else {
    gemm_split_k<<<dim3(32, 8, 1), 256, 0, stream>>>(
        h1hi, h1lo, wthi, wtlo, b2mu, params + 2, nullptr, nullptr, h2,
        1024, 4096, 4096, 4096, 1);
  }
  // scalars + last layer
  finalize_k<<<1, 256, 0, stream>>>(P, lkw1, lkb1, lkw2, lkb2, outp + 5120);
  layer3_k<<<1024, 256, 0, stream>>>(h2, w3mu, b3mu, outp);
}